// Round 4
// baseline (399.288 us; speedup 1.0000x reference)
//
#include <hip/hip_runtime.h>
#include <math.h>

// ---------------------------------------------------------------------------
// GATv2 2-layer GNN, fp32 in/out. N=50000, E=800000, F=128.
//   1. CSR by dst (memset -> count -> 3-kernel scan -> scatter)
//   2. prep_w: split W into bf16 hi/lo, transposed [n][k]
//   3. (opt) split_x: pre-split X into bf16 hi/lo planes
//   4. GEMM split-bf16 MFMA 3-term; split-input variant stages with pure
//      16B copies (no conversion VALU in K-loop)
//   5. aggregate v5 (16-lane groups, DPP reduce); layer-1 epilogue emits
//      hi/lo split planes directly (same bytes as fp32 bufC, bit-identical
//      values to the old in-GEMM split) -> feeds split-GEMM for layer 2
// ---------------------------------------------------------------------------

typedef short bf16x8 __attribute__((ext_vector_type(8)));
typedef float f32x4 __attribute__((ext_vector_type(4)));

__global__ void count_deg_kernel(const int* __restrict__ dst, int* __restrict__ deg, int E) {
    int i = blockIdx.x * blockDim.x + threadIdx.x;
    if (i < E) atomicAdd(&deg[dst[i]], 1);
}

// --- hierarchical scan: pass 1 -- per-block (256 nodes) sums ---
__global__ __launch_bounds__(256) void scan_blocksum_kernel(const int* __restrict__ deg,
                                                            int* __restrict__ blockSums, int n) {
    __shared__ int wsum[4];
    int tid = threadIdx.x;
    int idx = blockIdx.x * 256 + tid;
    int v = (idx < n) ? deg[idx] : 0;
    int lane = tid & 63, wid = tid >> 6;
    #pragma unroll
    for (int off = 32; off > 0; off >>= 1) v += __shfl_xor(v, off);
    if (lane == 0) wsum[wid] = v;
    __syncthreads();
    if (tid == 0) blockSums[blockIdx.x] = wsum[0] + wsum[1] + wsum[2] + wsum[3];
}

// --- pass 2 -- single-block exclusive scan of block sums ---
__global__ __launch_bounds__(256) void scan_sums_kernel(int* __restrict__ blockSums,
                                                        int* __restrict__ blockOffs,
                                                        int* __restrict__ totalOut, int n) {
    __shared__ int wsumExcl[4];
    __shared__ int sTotal;
    int tid = threadIdx.x, lane = tid & 63, wid = tid >> 6;
    int carry = 0;
    for (int base = 0; base < n; base += 256) {
        int idx = base + tid;
        int v = (idx < n) ? blockSums[idx] : 0;
        int incl = v;
        #pragma unroll
        for (int off = 1; off < 64; off <<= 1) {
            int t = __shfl_up(incl, off);
            if (lane >= off) incl += t;
        }
        if (lane == 63) wsumExcl[wid] = incl;
        __syncthreads();
        if (tid == 0) {
            int a = wsumExcl[0], b = wsumExcl[1], c = wsumExcl[2], d = wsumExcl[3];
            wsumExcl[0] = 0; wsumExcl[1] = a; wsumExcl[2] = a + b; wsumExcl[3] = a + b + c;
            sTotal = a + b + c + d;
        }
        __syncthreads();
        if (idx < n) blockOffs[idx] = carry + wsumExcl[wid] + (incl - v);
        carry += sTotal;
        __syncthreads();
    }
    if (tid == 0) *totalOut = carry;
}

// --- pass 3 -- local scan + block offset -> row_ptr / writeidx ---
__global__ __launch_bounds__(256) void scan_apply_kernel(const int* __restrict__ deg,
                                                         const int* __restrict__ blockOffs,
                                                         int* __restrict__ row_ptr,
                                                         int* __restrict__ writeidx, int n) {
    __shared__ int wsum[4];
    int tid = threadIdx.x, lane = tid & 63, wid = tid >> 6;
    int idx = blockIdx.x * 256 + tid;
    int v = (idx < n) ? deg[idx] : 0;
    int incl = v;
    #pragma unroll
    for (int off = 1; off < 64; off <<= 1) {
        int t = __shfl_up(incl, off);
        if (lane >= off) incl += t;
    }
    if (lane == 63) wsum[wid] = incl;
    __syncthreads();
    int woff = 0;
    #pragma unroll
    for (int w = 0; w < 4; ++w) woff += (w < wid) ? wsum[w] : 0;
    int excl = blockOffs[blockIdx.x] + woff + (incl - v);
    if (idx < n) { row_ptr[idx] = excl; writeidx[idx] = excl; }
}

__global__ void scatter_edges_kernel(const int* __restrict__ src, const int* __restrict__ dst,
                                     int* __restrict__ writeidx, int* __restrict__ csr_src, int E) {
    int i = blockIdx.x * blockDim.x + threadIdx.x;
    if (i < E) {
        int d = dst[i];
        int pos = atomicAdd(&writeidx[d], 1);
        csr_src[pos] = src[i];
    }
}

// ---------------------------------------------------------------------------
// Split each 128x128 fp32 W into bf16 hi/lo, transposed to [n][k].
// ---------------------------------------------------------------------------
__global__ __launch_bounds__(256) void prep_w_kernel(
    const float* __restrict__ W0, const float* __restrict__ W1,
    const float* __restrict__ W2, const float* __restrict__ W3,
    short* __restrict__ wt) {
    int mat = blockIdx.x >> 3;
    int chunk = blockIdx.x & 7;
    const float* W = (mat == 0) ? W0 : (mat == 1) ? W1 : (mat == 2) ? W2 : W3;
    short* hi = wt + (size_t)mat * 2 * 16384;
    short* lo = hi + 16384;
    int i0 = chunk * 2048;
    for (int i = i0 + threadIdx.x; i < i0 + 2048; i += 256) {
        int k = i >> 7, n = i & 127;
        float x = W[i];
        unsigned u = __float_as_uint(x);
        unsigned hu = u & 0xFFFF0000u;
        float lf = x - __uint_as_float(hu);
        hi[n * 128 + k] = (short)(hu >> 16);
        lo[n * 128 + k] = (short)(__float_as_uint(lf) >> 16);
    }
}

// ---------------------------------------------------------------------------
// Split fp32 matrix [rows][128] into bf16 hi/lo planes (row-major).
// One thread = 8 elems. total = rows*128.
// ---------------------------------------------------------------------------
__global__ __launch_bounds__(256) void split_x_kernel(const float* __restrict__ X,
                                                      short* __restrict__ Xh,
                                                      short* __restrict__ Xl,
                                                      size_t total) {
    size_t i = ((size_t)blockIdx.x * 256 + threadIdx.x) * 8;
    if (i >= total) return;
    float4 v0 = *(const float4*)&X[i];
    float4 v1 = *(const float4*)&X[i + 4];
    float f[8] = {v0.x, v0.y, v0.z, v0.w, v1.x, v1.y, v1.z, v1.w};
    bf16x8 hv, lv;
    #pragma unroll
    for (int j = 0; j < 8; ++j) {
        unsigned u = __float_as_uint(f[j]);
        unsigned hu = u & 0xFFFF0000u;
        float lf = f[j] - __uint_as_float(hu);
        hv[j] = (short)(hu >> 16);
        lv[j] = (short)(__float_as_uint(lf) >> 16);
    }
    *(bf16x8*)&Xh[i] = hv;
    *(bf16x8*)&Xl[i] = lv;
}

// ---------------------------------------------------------------------------
// Split-bf16 MFMA GEMM, fp32-input variant (in-kernel split; fallback path).
// ---------------------------------------------------------------------------
__global__ __launch_bounds__(256) void gemm_mfma_dual_kernel(
    const float* __restrict__ X, const short* __restrict__ wt,
    const float* __restrict__ b0, float* __restrict__ out0,
    const float* __restrict__ b1, float* __restrict__ out1,
    int Nrows) {
    const short* WTh = wt + (size_t)blockIdx.y * 2 * 16384;
    const short* WTl = WTh + 16384;
    const float* bias = blockIdx.y ? b1 : b0;
    float* out = blockIdx.y ? out1 : out0;

    __shared__ __attribute__((aligned(16))) short Ahi[128][40];
    __shared__ __attribute__((aligned(16))) short Alo[128][40];

    int tid = threadIdx.x;
    int w = tid >> 6, lane = tid & 63, q = lane >> 4, tr = lane & 15;
    int m0 = blockIdx.x * 128;
    int n0 = w * 32;

    f32x4 acc[8][2];
    #pragma unroll
    for (int a = 0; a < 8; ++a)
        #pragma unroll
        for (int b = 0; b < 2; ++b) acc[a][b] = (f32x4){0.f, 0.f, 0.f, 0.f};

    int srow = tid >> 3;        // 0..31
    int scol = (tid & 7) * 4;   // 0..28

    for (int kc = 0; kc < 128; kc += 32) {
        #pragma unroll
        for (int pass = 0; pass < 4; ++pass) {
            int r = srow + pass * 32;
            int gr = m0 + r; if (gr >= Nrows) gr = Nrows - 1;
            float4 v = *(const float4*)&X[(size_t)gr * 128 + kc + scol];
            float vv[4] = {v.x, v.y, v.z, v.w};
            short h[4], l[4];
            #pragma unroll
            for (int j = 0; j < 4; ++j) {
                unsigned u = __float_as_uint(vv[j]);
                unsigned hu = u & 0xFFFF0000u;
                float lf = vv[j] - __uint_as_float(hu);
                h[j] = (short)(hu >> 16);
                l[j] = (short)(__float_as_uint(lf) >> 16);
            }
            *(short4*)&Ahi[r][scol] = make_short4(h[0], h[1], h[2], h[3]);
            *(short4*)&Alo[r][scol] = make_short4(l[0], l[1], l[2], l[3]);
        }
        __syncthreads();

        bf16x8 bh[2], bl[2];
        #pragma unroll
        for (int nt = 0; nt < 2; ++nt) {
            size_t boff = (size_t)(n0 + nt * 16 + tr) * 128 + kc + q * 8;
            bh[nt] = *(const bf16x8*)&WTh[boff];
            bl[nt] = *(const bf16x8*)&WTl[boff];
        }

        #pragma unroll
        for (int mt = 0; mt < 8; ++mt) {
            bf16x8 ah = *(const bf16x8*)&Ahi[mt * 16 + tr][q * 8];
            bf16x8 al = *(const bf16x8*)&Alo[mt * 16 + tr][q * 8];
            #pragma unroll
            for (int nt = 0; nt < 2; ++nt) {
                acc[mt][nt] = __builtin_amdgcn_mfma_f32_16x16x32_bf16(ah, bh[nt], acc[mt][nt], 0, 0, 0);
                acc[mt][nt] = __builtin_amdgcn_mfma_f32_16x16x32_bf16(ah, bl[nt], acc[mt][nt], 0, 0, 0);
                acc[mt][nt] = __builtin_amdgcn_mfma_f32_16x16x32_bf16(al, bh[nt], acc[mt][nt], 0, 0, 0);
            }
        }
        __syncthreads();
    }

    #pragma unroll
    for (int nt = 0; nt < 2; ++nt) {
        float bv = bias[n0 + nt * 16 + tr];
        #pragma unroll
        for (int mt = 0; mt < 8; ++mt) {
            #pragma unroll
            for (int r = 0; r < 4; ++r) {
                int row = m0 + mt * 16 + q * 4 + r;
                if (row < Nrows)
                    out[(size_t)row * 128 + n0 + nt * 16 + tr] = acc[mt][nt][r] + bv;
            }
        }
    }
}

// ---------------------------------------------------------------------------
// Split-bf16 MFMA GEMM, pre-split-input variant: X given as hi/lo short
// planes [Nrows][128]. Staging = pure 16B copies (no conversion VALU).
// Per thread per chunk: 2 passes x (1 hi-load + 1 lo-load + 2 ds_write_b128).
// ---------------------------------------------------------------------------
__global__ __launch_bounds__(256) void gemm_mfma_split_kernel(
    const short* __restrict__ Xh, const short* __restrict__ Xlo,
    const short* __restrict__ wt,
    const float* __restrict__ b0, float* __restrict__ out0,
    const float* __restrict__ b1, float* __restrict__ out1,
    int Nrows) {
    const short* WTh = wt + (size_t)blockIdx.y * 2 * 16384;
    const short* WTl = WTh + 16384;
    const float* bias = blockIdx.y ? b1 : b0;
    float* out = blockIdx.y ? out1 : out0;

    __shared__ __attribute__((aligned(16))) short Ahi[128][40];
    __shared__ __attribute__((aligned(16))) short Alo[128][40];

    int tid = threadIdx.x;
    int w = tid >> 6, lane = tid & 63, q = lane >> 4, tr = lane & 15;
    int m0 = blockIdx.x * 128;
    int n0 = w * 32;

    f32x4 acc[8][2];
    #pragma unroll
    for (int a = 0; a < 8; ++a)
        #pragma unroll
        for (int b = 0; b < 2; ++b) acc[a][b] = (f32x4){0.f, 0.f, 0.f, 0.f};

    int srow = tid >> 2;        // 0..63
    int sc8 = (tid & 3) * 8;    // 0,8,16,24

    for (int kc = 0; kc < 128; kc += 32) {
        #pragma unroll
        for (int pass = 0; pass < 2; ++pass) {
            int r = srow + pass * 64;
            int gr = m0 + r; if (gr >= Nrows) gr = Nrows - 1;
            size_t goff = (size_t)gr * 128 + kc + sc8;
            *(bf16x8*)&Ahi[r][sc8] = *(const bf16x8*)&Xh[goff];
            *(bf16x8*)&Alo[r][sc8] = *(const bf16x8*)&Xlo[goff];
        }
        __syncthreads();

        bf16x8 bh[2], bl[2];
        #pragma unroll
        for (int nt = 0; nt < 2; ++nt) {
            size_t boff = (size_t)(n0 + nt * 16 + tr) * 128 + kc + q * 8;
            bh[nt] = *(const bf16x8*)&WTh[boff];
            bl[nt] = *(const bf16x8*)&WTl[boff];
        }

        #pragma unroll
        for (int mt = 0; mt < 8; ++mt) {
            bf16x8 ah = *(const bf16x8*)&Ahi[mt * 16 + tr][q * 8];
            bf16x8 al = *(const bf16x8*)&Alo[mt * 16 + tr][q * 8];
            #pragma unroll
            for (int nt = 0; nt < 2; ++nt) {
                acc[mt][nt] = __builtin_amdgcn_mfma_f32_16x16x32_bf16(ah, bh[nt], acc[mt][nt], 0, 0, 0);
                acc[mt][nt] = __builtin_amdgcn_mfma_f32_16x16x32_bf16(ah, bl[nt], acc[mt][nt], 0, 0, 0);
                acc[mt][nt] = __builtin_amdgcn_mfma_f32_16x16x32_bf16(al, bh[nt], acc[mt][nt], 0, 0, 0);
            }
        }
        __syncthreads();
    }

    #pragma unroll
    for (int nt = 0; nt < 2; ++nt) {
        float bv = bias[n0 + nt * 16 + tr];
        #pragma unroll
        for (int mt = 0; mt < 8; ++mt) {
            #pragma unroll
            for (int r = 0; r < 4; ++r) {
                int row = m0 + mt * 16 + q * 4 + r;
                if (row < Nrows)
                    out[(size_t)row * 128 + n0 + nt * 16 + tr] = acc[mt][nt][r] + bv;
            }
        }
    }
}

// ---------------------------------------------------------------------------
// Aggregation v5: 16-lane groups, 4 edges in flight per wave.
// If outSplit != nullptr: epilogue writes bf16 hi/lo planes [N][128]
// (bit-identical to the old in-GEMM split of the fp32 value) instead of fp32.
// ---------------------------------------------------------------------------
__global__ __launch_bounds__(256) void gat_aggregate_kernel(
    const float* __restrict__ xl, const float* __restrict__ xr,
    const float* __restrict__ att, const float* __restrict__ bias,
    const int* __restrict__ row_ptr, const int* __restrict__ csr_src,
    float* __restrict__ out, short* __restrict__ outSplit,
    int N, int applyRelu) {
    int wid = threadIdx.x >> 6;      // 0..3 -> node within block
    int lane = threadIdx.x & 63;
    int qlane = lane & 15;
    int qid = lane >> 4;
    int node = blockIdx.x * 4 + wid;
    if (node >= N) return;

    const float4* xl4 = (const float4*)xl;
    float4 xrL = ((const float4*)xr)[(size_t)node * 32 + qlane];
    float4 xrH = ((const float4*)xr)[(size_t)node * 32 + 16 + qlane];
    float4 atL = ((const float4*)att)[qlane];
    float4 atH = ((const float4*)att)[16 + qlane];

    int beg = row_ptr[node];
    int end = row_ptr[node + 1];

    float dsum = 0.f;
    float4 accL = {0.f, 0.f, 0.f, 0.f};
    float4 accH = {0.f, 0.f, 0.f, 0.f};

    for (int cbase = beg; cbase < end; cbase += 64) {
        int cnt = end - cbase;
        if (cnt > 64) cnt = 64;
        int myidx = (lane < cnt) ? csr_src[cbase + lane] : 0;  // coalesced
        int nq = (cnt + 3) >> 2;                               // quads of 4 edges

        for (int g = 0; g < nq; ++g) {
            int eidx = 4 * g + qid;
            int s = __shfl(myidx, eidx);
            float4 vL = xl4[(s << 5) + qlane];
            float4 vH = xl4[(s << 5) + 16 + qlane];

            float t, p;
            t = vL.x + xrL.x; t = t > 0.f ? t : 0.2f * t; p = t * atL.x;
            t = vL.y + xrL.y; t = t > 0.f ? t : 0.2f * t; p = fmaf(t, atL.y, p);
            t = vL.z + xrL.z; t = t > 0.f ? t : 0.2f * t; p = fmaf(t, atL.z, p);
            t = vL.w + xrL.w; t = t > 0.f ? t : 0.2f * t; p = fmaf(t, atL.w, p);
            t = vH.x + xrH.x; t = t > 0.f ? t : 0.2f * t; p = fmaf(t, atH.x, p);
            t = vH.y + xrH.y; t = t > 0.f ? t : 0.2f * t; p = fmaf(t, atH.y, p);
            t = vH.z + xrH.z; t = t > 0.f ? t : 0.2f * t; p = fmaf(t, atH.z, p);
            t = vH.w + xrH.w; t = t > 0.f ? t : 0.2f * t; p = fmaf(t, atH.w, p);

            p += __shfl_xor(p, 1);
            p += __shfl_xor(p, 2);
            p += __shfl_xor(p, 4);
            p += __shfl_xor(p, 8);

            float e = (eidx < cnt) ? __expf(p) : 0.f;
            dsum += e;
            accL.x = fmaf(e, vL.x, accL.x);
            accL.y = fmaf(e, vL.y, accL.y);
            accL.z = fmaf(e, vL.z, accL.z);
            accL.w = fmaf(e, vL.w, accL.w);
            accH.x = fmaf(e, vH.x, accH.x);
            accH.y = fmaf(e, vH.y, accH.y);
            accH.z = fmaf(e, vH.z, accH.z);
            accH.w = fmaf(e, vH.w, accH.w);
        }
    }

    #pragma unroll
    for (int off = 16; off <= 32; off <<= 1) {
        dsum += __shfl_xor(dsum, off);
        accL.x += __shfl_xor(accL.x, off);
        accL.y += __shfl_xor(accL.y, off);
        accL.z += __shfl_xor(accL.z, off);
        accL.w += __shfl_xor(accL.w, off);
        accH.x += __shfl_xor(accH.x, off);
        accH.y += __shfl_xor(accH.y, off);
        accH.z += __shfl_xor(accH.z, off);
        accH.w += __shfl_xor(accH.w, off);
    }

    float inv = dsum > 0.f ? 1.f / dsum : 0.f;
    float4 bvL = ((const float4*)bias)[qlane];
    float4 bvH = ((const float4*)bias)[16 + qlane];
    float4 oL, oH;
    oL.x = accL.x * inv + bvL.x; oL.y = accL.y * inv + bvL.y;
    oL.z = accL.z * inv + bvL.z; oL.w = accL.w * inv + bvL.w;
    oH.x = accH.x * inv + bvH.x; oH.y = accH.y * inv + bvH.y;
    oH.z = accH.z * inv + bvH.z; oH.w = accH.w * inv + bvH.w;
    if (applyRelu) {
        oL.x = fmaxf(oL.x, 0.f); oL.y = fmaxf(oL.y, 0.f);
        oL.z = fmaxf(oL.z, 0.f); oL.w = fmaxf(oL.w, 0.f);
        oH.x = fmaxf(oH.x, 0.f); oH.y = fmaxf(oH.y, 0.f);
        oH.z = fmaxf(oH.z, 0.f); oH.w = fmaxf(oH.w, 0.f);
    }
    if (lane < 16) {
        if (outSplit) {
            short* oh = outSplit;
            short* ol = outSplit + (size_t)N * 128;
            float fo[8] = {oL.x, oL.y, oL.z, oL.w, oH.x, oH.y, oH.z, oH.w};
            short hh[8], ll[8];
            #pragma unroll
            for (int j = 0; j < 8; ++j) {
                unsigned u = __float_as_uint(fo[j]);
                unsigned hu = u & 0xFFFF0000u;
                float lf = fo[j] - __uint_as_float(hu);
                hh[j] = (short)(hu >> 16);
                ll[j] = (short)(__float_as_uint(lf) >> 16);
            }
            size_t base = (size_t)node * 128 + qlane * 4;
            *(short4*)&oh[base]      = make_short4(hh[0], hh[1], hh[2], hh[3]);
            *(short4*)&oh[base + 64] = make_short4(hh[4], hh[5], hh[6], hh[7]);
            *(short4*)&ol[base]      = make_short4(ll[0], ll[1], ll[2], ll[3]);
            *(short4*)&ol[base + 64] = make_short4(ll[4], ll[5], ll[6], ll[7]);
        } else {
            ((float4*)out)[(size_t)node * 32 + qlane] = oL;
            ((float4*)out)[(size_t)node * 32 + 16 + qlane] = oH;
        }
    }
}

// ---------------------------------------------------------------------------

extern "C" void kernel_launch(void* const* d_in, const int* in_sizes, int n_in,
                              void* d_out, int out_size, void* d_ws, size_t ws_size,
                              hipStream_t stream) {
    const float* x    = (const float*)d_in[0];
    const int* eidx   = (const int*)d_in[1];
    const float* Wl1  = (const float*)d_in[2];
    const float* bl1  = (const float*)d_in[3];
    const float* Wr1  = (const float*)d_in[4];
    const float* br1  = (const float*)d_in[5];
    const float* att1 = (const float*)d_in[6];
    const float* b1   = (const float*)d_in[7];
    const float* Wl2  = (const float*)d_in[8];
    const float* bl2  = (const float*)d_in[9];
    const float* Wr2  = (const float*)d_in[10];
    const float* br2  = (const float*)d_in[11];
    const float* att2 = (const float*)d_in[12];
    const float* b2   = (const float*)d_in[13];

    const int N = in_sizes[0] / 128;
    const int E = in_sizes[1] / 2;
    const int* src = eidx;
    const int* dst = eidx + E;

    const int nBlk = (N + 255) / 256;

    // workspace layout
    size_t NF = (size_t)N * 128;
    float* bufA = (float*)d_ws;            // xl
    float* bufB = bufA + NF;               // xr
    short* csplit = (short*)(bufB + NF);   // layer-1 output, hi/lo planes (= old bufC slot, NF floats)
    int* deg       = (int*)((char*)csplit + NF * 4);  // [N]
    int* row_ptr   = deg + N;              // [N+1]
    int* writeidx  = row_ptr + (N + 1);    // [N]
    int* csr_src   = writeidx + N;         // [E]
    int* blockSums = csr_src + E;          // [nBlk]
    int* blockOffs = blockSums + nBlk;     // [nBlk]
    short* wt      = (short*)(blockOffs + nBlk);      // 4 matrices x (hi+lo) x 16384
    short* xsplit  = wt + 4 * 2 * 16384;   // optional: X hi/lo planes (2*NF shorts)

    size_t needFull = (size_t)((char*)(xsplit + 2 * NF) - (char*)d_ws);
    bool useSplitX = (ws_size >= needFull);

    float* outF = (float*)d_out;

    // --- CSR build + W prep ---
    hipMemsetAsync(deg, 0, (size_t)N * sizeof(int), stream);
    prep_w_kernel<<<32, 256, 0, stream>>>(Wl1, Wr1, Wl2, Wr2, wt);
    count_deg_kernel<<<(E + 255) / 256, 256, 0, stream>>>(dst, deg, E);
    scan_blocksum_kernel<<<nBlk, 256, 0, stream>>>(deg, blockSums, N);
    scan_sums_kernel<<<1, 256, 0, stream>>>(blockSums, blockOffs, &row_ptr[N], nBlk);
    scan_apply_kernel<<<nBlk, 256, 0, stream>>>(deg, blockOffs, row_ptr, writeidx, N);
    scatter_edges_kernel<<<(E + 255) / 256, 256, 0, stream>>>(src, dst, writeidx, csr_src, E);

    dim3 gemmGrid((N + 127) / 128, 2);
    dim3 aggGrid((N + 3) / 4);

    // --- layer 1 ---
    if (useSplitX) {
        int sBlk = (int)((NF / 8 + 255) / 256);
        split_x_kernel<<<sBlk, 256, 0, stream>>>(x, xsplit, xsplit + NF, NF);
        gemm_mfma_split_kernel<<<gemmGrid, 256, 0, stream>>>(xsplit, xsplit + NF, wt,
                                                             bl1, bufA, br1, bufB, N);
    } else {
        gemm_mfma_dual_kernel<<<gemmGrid, 256, 0, stream>>>(x, wt, bl1, bufA, br1, bufB, N);
    }
    gat_aggregate_kernel<<<aggGrid, 256, 0, stream>>>(bufA, bufB, att1, b1, row_ptr, csr_src,
                                                      nullptr, csplit, N, 1);
    // --- layer 2 (input pre-split by aggregate epilogue) ---
    gemm_mfma_split_kernel<<<gemmGrid, 256, 0, stream>>>(csplit, csplit + NF, wt + 2 * 2 * 16384,
                                                         bl2, bufA, br2, bufB, N);
    gat_aggregate_kernel<<<aggGrid, 256, 0, stream>>>(bufA, bufB, att2, b2, row_ptr, csr_src,
                                                      outF, nullptr, N, 0);
}